// Round 5
// baseline (472.492 us; speedup 1.0000x reference)
//
#include <hip/hip_runtime.h>
#include <math.h>

#define NB 4
#define NN 4096
#define KSEL 204
#define NBINS 512
#define CANDN 320
#define QKSCALE 0.31622776601683794f

// workspace layout in floats
#define WS_Q 0
#define WS_KT (NB * NN * 10)       // 163840
#define WS_V (2 * NB * NN * 10)    // 327680

#define SEQ_PER_BLOCK 16

__global__ __launch_bounds__(256, 4) void featqkv_kernel(
    const float* __restrict__ x,
    const float* __restrict__ w2, const float* __restrict__ b2,
    const float* __restrict__ w3, const float* __restrict__ b3,
    const float* __restrict__ w4, const float* __restrict__ b4,
    const float* __restrict__ w5, const float* __restrict__ b5,
    const float* __restrict__ w6, const float* __restrict__ b6,
    const float* __restrict__ w7, const float* __restrict__ b7,
    const float* __restrict__ wq, const float* __restrict__ bq,
    const float* __restrict__ wk, const float* __restrict__ bk,
    const float* __restrict__ wv, const float* __restrict__ bv,
    float* __restrict__ q_out, float* __restrict__ kT_out, float* __restrict__ v_out,
    float* __restrict__ out_pooled)
{
    __shared__ float xs[SEQ_PER_BLOCK * 450];   // [seq][15][30], cols 24..29 zero
    __shared__ float wpad[14 * 105];            // [ch][15][7], taps >= h zero
    __shared__ float bconv[14];
    __shared__ float wqkv[420];
    __shared__ float bqkv[30];
    __shared__ float feats[SEQ_PER_BLOCK * 14];

    const int t = threadIdx.x;
    const int g0 = blockIdx.x * SEQ_PER_BLOCK;

    if (blockIdx.x == 0 && t < 8) out_pooled[t] = 0.f;  // zero pooled accumulators

    // ---- stage x (float4, padded layout); zero the pad columns ----
    const float4* xg4 = reinterpret_cast<const float4*>(x + (size_t)g0 * 360);
    for (int i = t; i < SEQ_PER_BLOCK * 90; i += 256) {
        const int seq = i / 90;
        const int i4 = i % 90;
        const int c = i4 / 6;
        const int u = (i4 % 6) * 4;
        const float4 v = xg4[i];
        float* dst = &xs[seq * 450 + c * 30 + u];
        dst[0] = v.x; dst[1] = v.y; dst[2] = v.z; dst[3] = v.w;
    }
    for (int i = t; i < SEQ_PER_BLOCK * 90; i += 256) {  // 15*6 pad slots per seq
        const int seq = i / 90;
        const int rem = i % 90;
        const int c = rem / 6;
        const int u = 24 + rem % 6;
        xs[seq * 450 + c * 30 + u] = 0.f;
    }
    // ---- stage padded weights: single writer per word, pad written as 0 ----
    for (int i = t; i < 14 * 105; i += 256) {
        const int ch = i / 105;
        const int rem = i % 105;
        const int c = rem / 7;
        const int j = rem % 7;
        float v = 0.f;
        if (ch < 3)       { if (j < 2) v = w2[ch * 30 + c * 2 + j]; }
        else if (ch < 6)  { if (j < 3) v = w3[(ch - 3) * 45 + c * 3 + j]; }
        else if (ch < 9)  { if (j < 4) v = w4[(ch - 6) * 60 + c * 4 + j]; }
        else if (ch < 11) { if (j < 5) v = w5[(ch - 9) * 75 + c * 5 + j]; }
        else if (ch < 13) { if (j < 6) v = w6[(ch - 11) * 90 + c * 6 + j]; }
        else              { v = w7[c * 7 + j]; }
        wpad[i] = v;
    }
    if (t < 3) bconv[t] = b2[t];
    else if (t < 6) bconv[t] = b3[t - 3];
    else if (t < 9) bconv[t] = b4[t - 6];
    else if (t < 11) bconv[t] = b5[t - 9];
    else if (t < 13) bconv[t] = b6[t - 11];
    else if (t == 13) bconv[t] = b7[0];
    for (int i = t; i < 140; i += 256) wqkv[i] = wq[i];
    for (int i = t; i < 140; i += 256) wqkv[140 + i] = wk[i];
    for (int i = t; i < 140; i += 256) wqkv[280 + i] = wv[i];
    if (t < 10) bqkv[t] = bq[t];
    else if (t < 20) bqkv[t] = bk[t - 10];
    else if (t < 30) bqkv[t] = bv[t - 20];
    __syncthreads();

    const int seq = t >> 4;
    const int wkr = t & 15;

    if (wkr < 14) {
        const int ch = wkr;
        const int h = (ch < 3) ? 2 : (ch < 6) ? 3 : (ch < 9) ? 4 :
                      (ch < 11) ? 5 : (ch < 13) ? 6 : 7;
        const int T = 25 - h;

        float acc[23];
#pragma unroll
        for (int i2 = 0; i2 < 23; i2++) acc[i2] = 0.f;
        const float* xrow = &xs[seq * 450];
        const float* wrow = &wpad[ch * 105];
        for (int c = 0; c < 15; c++) {
            float xr[30];
#pragma unroll
            for (int u = 0; u < 30; u++) xr[u] = xrow[c * 30 + u];
#pragma unroll
            for (int j = 0; j < 7; j++) {
                const float wv_ = wrow[c * 7 + j];
#pragma unroll
                for (int tt = 0; tt < 23; tt++)
                    acc[tt] = fmaf(xr[tt + j], wv_, acc[tt]);
            }
        }
        float m = -1e30f;
#pragma unroll
        for (int tt = 0; tt < 23; tt++) {
            if (tt < T) m = fmaxf(m, acc[tt]);   // runtime mask only here
        }
        feats[seq * 14 + ch] = fmaxf(m + bconv[ch], 0.f);
    }
    __syncthreads();

    const int g = g0 + seq;
    const int b_ = g >> 12;
    const int n_ = g & 4095;
    for (int o = wkr; o < 30; o += 16) {
        const int type = o / 10;
        const int comp = o % 10;
        const float* wrow = &wqkv[type * 140 + comp * 14];
        const float* frow = &feats[seq * 14];
        float a = bqkv[type * 10 + comp];
#pragma unroll
        for (int ii = 0; ii < 14; ii++) a = fmaf(frow[ii], wrow[ii], a);
        if (type == 0) q_out[(size_t)g * 10 + comp] = a;
        else if (type == 1) kT_out[((size_t)b_ * 10 + comp) * NN + n_] = a;
        else v_out[(size_t)g * 10 + comp] = a;
    }
}

__device__ __forceinline__ float dec_key(unsigned int k) {
    return (k & 0x80000000u) ? __uint_as_float(k ^ 0x80000000u)
                             : __uint_as_float(~k);
}
__device__ __forceinline__ unsigned int enc_key(float s) {
    unsigned int u = __float_as_uint(s);
    return (u & 0x80000000u) ? ~u : (u | 0x80000000u);
}

// 256 threads / 2 rows per block. Scores in registers; linear-histogram rank.
__global__ __launch_bounds__(256, 6) void attn_kernel(
    const float* __restrict__ qbuf, const float* __restrict__ kTbuf,
    const float* __restrict__ vbuf,
    const float* __restrict__ w_attn, const float* __restrict__ b_attn,
    const float* __restrict__ w_mil, const float* __restrict__ b_mil,
    float* __restrict__ out_probs, float* __restrict__ out_pooled)
{
    __shared__ unsigned int base_[NBINS];
    __shared__ unsigned int bc_[NBINS];
    __shared__ unsigned long long cand[CANDN];
    __shared__ float hpart[4], lpart[4], fpart[4];
    __shared__ unsigned int wtot[4];
    __shared__ float ctxp[40];
    __shared__ float ctx_sh[10];
    __shared__ float attn_sh[14];

    const int t = threadIdx.x;
    const int lane = t & 63;
    const int w = t >> 6;
    const int row0 = blockIdx.x * 2;
    const int b_ = row0 >> 12;

    // ---- P1: scores for both rows (k loaded once) ----
    float qA[10], qB[10];
#pragma unroll
    for (int c = 0; c < 10; c++) {
        qA[c] = qbuf[(size_t)row0 * 10 + c];
        qB[c] = qbuf[(size_t)(row0 + 1) * 10 + c];
    }
    const float* kTb = kTbuf + (size_t)b_ * 10 * NN;
    float scA[16], scB[16];
    float hiA = -1e30f, loA = 1e30f, hiB = -1e30f, loB = 1e30f;
#pragma unroll
    for (int i = 0; i < 4; i++) {
        float4 aA = make_float4(0.f, 0.f, 0.f, 0.f);
        float4 aB = make_float4(0.f, 0.f, 0.f, 0.f);
#pragma unroll
        for (int c = 0; c < 10; c++) {
            const float4 kv = reinterpret_cast<const float4*>(kTb + c * NN)[i * 256 + t];
            aA.x = fmaf(qA[c], kv.x, aA.x); aA.y = fmaf(qA[c], kv.y, aA.y);
            aA.z = fmaf(qA[c], kv.z, aA.z); aA.w = fmaf(qA[c], kv.w, aA.w);
            aB.x = fmaf(qB[c], kv.x, aB.x); aB.y = fmaf(qB[c], kv.y, aB.y);
            aB.z = fmaf(qB[c], kv.z, aB.z); aB.w = fmaf(qB[c], kv.w, aB.w);
        }
        scA[i * 4 + 0] = aA.x; scA[i * 4 + 1] = aA.y; scA[i * 4 + 2] = aA.z; scA[i * 4 + 3] = aA.w;
        scB[i * 4 + 0] = aB.x; scB[i * 4 + 1] = aB.y; scB[i * 4 + 2] = aB.z; scB[i * 4 + 3] = aB.w;
        hiA = fmaxf(hiA, fmaxf(fmaxf(aA.x, aA.y), fmaxf(aA.z, aA.w)));
        loA = fminf(loA, fminf(fminf(aA.x, aA.y), fminf(aA.z, aA.w)));
        hiB = fmaxf(hiB, fmaxf(fmaxf(aB.x, aB.y), fmaxf(aB.z, aB.w)));
        loB = fminf(loB, fminf(fminf(aB.x, aB.y), fminf(aB.z, aB.w)));
    }
#pragma unroll
    for (int off = 32; off > 0; off >>= 1) {
        hiA = fmaxf(hiA, __shfl_xor(hiA, off));
        loA = fminf(loA, __shfl_xor(loA, off));
        hiB = fmaxf(hiB, __shfl_xor(hiB, off));
        loB = fminf(loB, __shfl_xor(loB, off));
    }

#pragma unroll 1
    for (int rr = 0; rr < 2; rr++) {
        const int row = row0 + rr;
        // broadcast hi/lo for this row; zero hist + cand under one barrier
        if (lane == 0) {
            hpart[w] = rr ? hiB : hiA;
            lpart[w] = rr ? loB : loA;
        }
        base_[2 * t] = 0u; base_[2 * t + 1] = 0u;
        if (t < CANDN - 256) cand[256 + t] = 0ULL;
        cand[t] = 0ULL;
        __syncthreads();
        const float hi = fmaxf(fmaxf(hpart[0], hpart[1]), fmaxf(hpart[2], hpart[3]));
        const float lo = fminf(fminf(lpart[0], lpart[1]), fminf(lpart[2], lpart[3]));
        const bool degen = (hi <= lo);

        float pv = 0.f;
        int jj = 0, p = KSEL;
        bool selected = false;
        const float smax = hi * QKSCALE;

        if (!degen) {
            const float scale = (float)(NBINS - 1) / (hi - lo);
            int bins[16];

            // ---- P2: histogram (bins cached in regs) ----
#pragma unroll
            for (int i = 0; i < 16; i++) {
                const float s = rr ? scB[i] : scA[i];
                const int bin = (int)fminf((s - lo) * scale, (float)(NBINS - 1));
                bins[i] = bin;
                atomicAdd(&base_[bin], 1u);
            }
            __syncthreads();

            // ---- P3: suffix scan -> base (pristine) + bc (mutable) ----
            {
                const unsigned int c0 = base_[2 * t];
                const unsigned int c1 = base_[2 * t + 1];
                const unsigned int T_ = c0 + c1;
                unsigned int acc = T_;
#pragma unroll
                for (int off = 1; off < 64; off <<= 1) {
                    unsigned int o = __shfl_down(acc, off);
                    if (lane + off < 64) acc += o;
                }
                if (lane == 0) wtot[w] = acc;
                __syncthreads();
                unsigned int tail = 0u;
#pragma unroll
                for (int w2 = 1; w2 < 4; w2++) if (w2 > w) tail += wtot[w2];
                const unsigned int A = (acc - T_) + tail;
                base_[2 * t + 1] = A;
                base_[2 * t] = A + c1;
                bc_[2 * t + 1] = A;
                bc_[2 * t] = A + c1;
            }
            __syncthreads();

            // ---- P4: scatter candidates ----
#pragma unroll
            for (int i = 0; i < 16; i++) {
                const int bin = bins[i];
                const unsigned int bs = base_[bin];
                if (bs < KSEL) {
                    const unsigned int pos = atomicAdd(&bc_[bin], 1u);
                    if (pos < CANDN) {
                        const float s = rr ? scB[i] : scA[i];
                        const int j = (i >> 2) * 1024 + t * 4 + (i & 3);
                        cand[pos] = (((unsigned long long)enc_key(s)) << 16)
                                  | (unsigned long long)(4095 - j);
                    }
                }
            }
            __syncthreads();

            // ---- P5: within-bin rank -> exact sorted position ----
            if (t < CANDN) {
                const unsigned long long mine = cand[t];
                if (mine != 0ULL) {
                    const float s = dec_key((unsigned int)(mine >> 16));
                    const int bin = (int)fminf((s - lo) * scale, (float)(NBINS - 1));
                    const unsigned int bs = base_[bin];
                    unsigned int e2 = (bin > 0) ? base_[bin - 1] : 4096u;
                    if (e2 > CANDN) e2 = CANDN;
                    unsigned int rank = 0;
                    for (unsigned int s2 = bs; s2 < e2; s2++)
                        rank += (cand[s2] > mine) ? 1u : 0u;
                    const unsigned int pp = bs + rank;
                    if (pp < KSEL) {
                        selected = true;
                        p = (int)pp;
                        jj = 4095 - (int)(mine & 0xFFFFu);
                        pv = expf(s * QKSCALE - smax);
                    }
                }
            }
        } else {
            if (t < KSEL) { selected = true; p = t; jj = t; pv = 1.f; }
        }

        // ---- P6: softmax denom ----
        float dsum = pv;
#pragma unroll
        for (int off = 32; off > 0; off >>= 1) dsum += __shfl_xor(dsum, off);
        if (lane == 0) fpart[w] = dsum;
        __syncthreads();
        const float inv = 1.f / (fpart[0] + fpart[1] + fpart[2] + fpart[3]);

        // ---- P7: probs out + ctx ----
        float cx0 = 0.f, cx1 = 0.f, cx2 = 0.f, cx3 = 0.f, cx4 = 0.f;
        float cx5 = 0.f, cx6 = 0.f, cx7 = 0.f, cx8 = 0.f, cx9 = 0.f;
        if (selected) {
            const float pn = pv * inv;
            out_probs[(size_t)row * KSEL + p] = pn;
            const float* vr = vbuf + ((size_t)b_ * NN + (size_t)jj) * 10;
            const float2 v01 = reinterpret_cast<const float2*>(vr)[0];
            const float2 v23 = reinterpret_cast<const float2*>(vr)[1];
            const float2 v45 = reinterpret_cast<const float2*>(vr)[2];
            const float2 v67 = reinterpret_cast<const float2*>(vr)[3];
            const float2 v89 = reinterpret_cast<const float2*>(vr)[4];
            cx0 = pn * v01.x; cx1 = pn * v01.y;
            cx2 = pn * v23.x; cx3 = pn * v23.y;
            cx4 = pn * v45.x; cx5 = pn * v45.y;
            cx6 = pn * v67.x; cx7 = pn * v67.y;
            cx8 = pn * v89.x; cx9 = pn * v89.y;
        }
#pragma unroll
        for (int off = 32; off > 0; off >>= 1) {
            cx0 += __shfl_xor(cx0, off); cx1 += __shfl_xor(cx1, off);
            cx2 += __shfl_xor(cx2, off); cx3 += __shfl_xor(cx3, off);
            cx4 += __shfl_xor(cx4, off); cx5 += __shfl_xor(cx5, off);
            cx6 += __shfl_xor(cx6, off); cx7 += __shfl_xor(cx7, off);
            cx8 += __shfl_xor(cx8, off); cx9 += __shfl_xor(cx9, off);
        }
        if (lane == 0) {
            ctxp[w * 10 + 0] = cx0; ctxp[w * 10 + 1] = cx1; ctxp[w * 10 + 2] = cx2;
            ctxp[w * 10 + 3] = cx3; ctxp[w * 10 + 4] = cx4; ctxp[w * 10 + 5] = cx5;
            ctxp[w * 10 + 6] = cx6; ctxp[w * 10 + 7] = cx7; ctxp[w * 10 + 8] = cx8;
            ctxp[w * 10 + 9] = cx9;
        }
        __syncthreads();
        if (t < 10) ctx_sh[t] = ctxp[t] + ctxp[10 + t] + ctxp[20 + t] + ctxp[30 + t];
        __syncthreads();

        // ---- P8: attn projection + mil logits -> atomic pooled ----
        if (t < 14) {
            float a = b_attn[t];
#pragma unroll
            for (int d = 0; d < 10; d++) a = fmaf(ctx_sh[d], w_attn[t * 10 + d], a);
            attn_sh[t] = a;
        }
        __syncthreads();
        if (t < 2) {
            float lg = b_mil[t];
#pragma unroll
            for (int ii = 0; ii < 14; ii++) lg = fmaf(attn_sh[ii], w_mil[t * 14 + ii], lg);
            atomicAdd(&out_pooled[b_ * 2 + t], lg * (1.f / 4096.f));
        }
        __syncthreads();   // protect shared buffers before next row
    }
}

extern "C" void kernel_launch(void* const* d_in, const int* in_sizes, int n_in,
                              void* d_out, int out_size, void* d_ws, size_t ws_size,
                              hipStream_t stream) {
    const float* x  = (const float*)d_in[0];
    const float* w2 = (const float*)d_in[1];  const float* b2 = (const float*)d_in[2];
    const float* w3 = (const float*)d_in[3];  const float* b3 = (const float*)d_in[4];
    const float* w4 = (const float*)d_in[5];  const float* b4 = (const float*)d_in[6];
    const float* w5 = (const float*)d_in[7];  const float* b5 = (const float*)d_in[8];
    const float* w6 = (const float*)d_in[9];  const float* b6 = (const float*)d_in[10];
    const float* w7 = (const float*)d_in[11]; const float* b7 = (const float*)d_in[12];
    const float* wq = (const float*)d_in[13]; const float* bq = (const float*)d_in[14];
    const float* wk = (const float*)d_in[15]; const float* bk = (const float*)d_in[16];
    const float* wv = (const float*)d_in[17]; const float* bv = (const float*)d_in[18];
    const float* wat = (const float*)d_in[19]; const float* bat = (const float*)d_in[20];
    const float* wm = (const float*)d_in[21];  const float* bm = (const float*)d_in[22];

    float* ws = (float*)d_ws;
    float* qb = ws + WS_Q;
    float* kT = ws + WS_KT;
    float* vb = ws + WS_V;
    float* out = (float*)d_out;

    hipLaunchKernelGGL(featqkv_kernel, dim3(NB * NN / SEQ_PER_BLOCK), dim3(256), 0, stream,
                       x, w2, b2, w3, b3, w4, b4, w5, b5, w6, b6, w7, b7,
                       wq, bq, wk, bk, wv, bv, qb, kT, vb, out);
    hipLaunchKernelGGL(attn_kernel, dim3(NB * NN / 2), dim3(256), 0, stream,
                       qb, kT, vb, wat, bat, wm, bm, out + 8, out);
}

// Round 6
// 363.721 us; speedup vs baseline: 1.2990x; 1.2990x over previous
//
#include <hip/hip_runtime.h>
#include <math.h>

#define NB 4
#define NN 4096
#define KSEL 204
#define NBINS 512
#define CANDN 320
#define QKSCALE 0.31622776601683794f

// workspace layout in floats
#define WS_Q 0
#define WS_KT (NB * NN * 10)       // 163840
#define WS_V (2 * NB * NN * 10)    // 327680

#define SEQ_PER_BLOCK 16

__global__ __launch_bounds__(256, 4) void featqkv_kernel(
    const float* __restrict__ x,
    const float* __restrict__ w2, const float* __restrict__ b2,
    const float* __restrict__ w3, const float* __restrict__ b3,
    const float* __restrict__ w4, const float* __restrict__ b4,
    const float* __restrict__ w5, const float* __restrict__ b5,
    const float* __restrict__ w6, const float* __restrict__ b6,
    const float* __restrict__ w7, const float* __restrict__ b7,
    const float* __restrict__ wq, const float* __restrict__ bq,
    const float* __restrict__ wk, const float* __restrict__ bk,
    const float* __restrict__ wv, const float* __restrict__ bv,
    float* __restrict__ q_out, float* __restrict__ kT_out, float* __restrict__ v_out,
    float* __restrict__ out_pooled)
{
    __shared__ float xs[SEQ_PER_BLOCK * 450];   // [seq][15][30], cols 24..29 zero
    __shared__ float wpad[14 * 105];            // [ch][15][7], taps >= h zero
    __shared__ float bconv[14];
    __shared__ float wqkv[420];
    __shared__ float bqkv[30];
    __shared__ float feats[SEQ_PER_BLOCK * 14];

    const int t = threadIdx.x;
    const int g0 = blockIdx.x * SEQ_PER_BLOCK;

    if (blockIdx.x == 0 && t < 8) out_pooled[t] = 0.f;  // zero pooled accumulators

    // ---- stage x (float4, padded layout); zero the pad columns ----
    const float4* xg4 = reinterpret_cast<const float4*>(x + (size_t)g0 * 360);
    for (int i = t; i < SEQ_PER_BLOCK * 90; i += 256) {
        const int seq = i / 90;
        const int i4 = i % 90;
        const int c = i4 / 6;
        const int u = (i4 % 6) * 4;
        const float4 v = xg4[i];
        float* dst = &xs[seq * 450 + c * 30 + u];
        dst[0] = v.x; dst[1] = v.y; dst[2] = v.z; dst[3] = v.w;
    }
    for (int i = t; i < SEQ_PER_BLOCK * 90; i += 256) {  // 15*6 pad slots per seq
        const int seq = i / 90;
        const int rem = i % 90;
        const int c = rem / 6;
        const int u = 24 + rem % 6;
        xs[seq * 450 + c * 30 + u] = 0.f;
    }
    // ---- stage padded weights: single writer per word, pad written as 0 ----
    for (int i = t; i < 14 * 105; i += 256) {
        const int ch = i / 105;
        const int rem = i % 105;
        const int c = rem / 7;
        const int j = rem % 7;
        float v = 0.f;
        if (ch < 3)       { if (j < 2) v = w2[ch * 30 + c * 2 + j]; }
        else if (ch < 6)  { if (j < 3) v = w3[(ch - 3) * 45 + c * 3 + j]; }
        else if (ch < 9)  { if (j < 4) v = w4[(ch - 6) * 60 + c * 4 + j]; }
        else if (ch < 11) { if (j < 5) v = w5[(ch - 9) * 75 + c * 5 + j]; }
        else if (ch < 13) { if (j < 6) v = w6[(ch - 11) * 90 + c * 6 + j]; }
        else              { v = w7[c * 7 + j]; }
        wpad[i] = v;
    }
    if (t < 3) bconv[t] = b2[t];
    else if (t < 6) bconv[t] = b3[t - 3];
    else if (t < 9) bconv[t] = b4[t - 6];
    else if (t < 11) bconv[t] = b5[t - 9];
    else if (t < 13) bconv[t] = b6[t - 11];
    else if (t == 13) bconv[t] = b7[0];
    for (int i = t; i < 140; i += 256) wqkv[i] = wq[i];
    for (int i = t; i < 140; i += 256) wqkv[140 + i] = wk[i];
    for (int i = t; i < 140; i += 256) wqkv[280 + i] = wv[i];
    if (t < 10) bqkv[t] = bq[t];
    else if (t < 20) bqkv[t] = bk[t - 10];
    else if (t < 30) bqkv[t] = bv[t - 20];
    __syncthreads();

    const int seq = t >> 4;
    const int wkr = t & 15;

    if (wkr < 14) {
        const int ch = wkr;
        const int h = (ch < 3) ? 2 : (ch < 6) ? 3 : (ch < 9) ? 4 :
                      (ch < 11) ? 5 : (ch < 13) ? 6 : 7;
        const int T = 25 - h;

        float acc[23];
#pragma unroll
        for (int i2 = 0; i2 < 23; i2++) acc[i2] = 0.f;
        const float* xrow = &xs[seq * 450];
        const float* wrow = &wpad[ch * 105];
        for (int c = 0; c < 15; c++) {
            float xr[30];
#pragma unroll
            for (int u = 0; u < 30; u++) xr[u] = xrow[c * 30 + u];
#pragma unroll
            for (int j = 0; j < 7; j++) {
                const float wv_ = wrow[c * 7 + j];
#pragma unroll
                for (int tt = 0; tt < 23; tt++)
                    acc[tt] = fmaf(xr[tt + j], wv_, acc[tt]);
            }
        }
        float m = -1e30f;
#pragma unroll
        for (int tt = 0; tt < 23; tt++) {
            if (tt < T) m = fmaxf(m, acc[tt]);   // runtime mask only here
        }
        feats[seq * 14 + ch] = fmaxf(m + bconv[ch], 0.f);
    }
    __syncthreads();

    const int g = g0 + seq;
    const int b_ = g >> 12;
    const int n_ = g & 4095;
    for (int o = wkr; o < 30; o += 16) {
        const int type = o / 10;
        const int comp = o % 10;
        const float* wrow = &wqkv[type * 140 + comp * 14];
        const float* frow = &feats[seq * 14];
        float a = bqkv[type * 10 + comp];
#pragma unroll
        for (int ii = 0; ii < 14; ii++) a = fmaf(frow[ii], wrow[ii], a);
        if (type == 0) q_out[(size_t)g * 10 + comp] = a;
        else if (type == 1) kT_out[((size_t)b_ * 10 + comp) * NN + n_] = a;
        else v_out[(size_t)g * 10 + comp] = a;
    }
}

__device__ __forceinline__ float dec_key(unsigned int k) {
    return (k & 0x80000000u) ? __uint_as_float(k ^ 0x80000000u)
                             : __uint_as_float(~k);
}
__device__ __forceinline__ unsigned int enc_key(float s) {
    unsigned int u = __float_as_uint(s);
    return (u & 0x80000000u) ? ~u : (u | 0x80000000u);
}

// 256 threads / 2 rows per block. Row A scores in regs, row B scores in LDS.
// kT loaded once per pair -> halves L2 traffic vs G=1.
__global__ __launch_bounds__(256, 4) void attn_kernel(
    const float* __restrict__ qbuf, const float* __restrict__ kTbuf,
    const float* __restrict__ vbuf,
    const float* __restrict__ w_attn, const float* __restrict__ b_attn,
    const float* __restrict__ w_mil, const float* __restrict__ b_mil,
    float* __restrict__ out_probs, float* __restrict__ out_pooled)
{
    __shared__ __align__(16) float suB[NN];     // row B raw scores (16 KB)
    __shared__ unsigned int base_[NBINS];
    __shared__ unsigned int bc_[NBINS];
    __shared__ unsigned long long cand[CANDN];
    __shared__ float hpart[4], lpart[4], fpart[4];
    __shared__ unsigned int wtot[4];
    __shared__ float ctxp[40];
    __shared__ float ctx_sh[10];
    __shared__ float attn_sh[14];

    const int t = threadIdx.x;
    const int lane = t & 63;
    const int w = t >> 6;
    const int row0 = blockIdx.x * 2;
    const int b_ = row0 >> 12;

    // ---- P1: scores for both rows (kT loaded once); A->regs, B->LDS ----
    float qA[10], qB[10];
#pragma unroll
    for (int c = 0; c < 10; c++) {
        qA[c] = qbuf[(size_t)row0 * 10 + c];
        qB[c] = qbuf[(size_t)(row0 + 1) * 10 + c];
    }
    const float* kTb = kTbuf + (size_t)b_ * 10 * NN;
    float scA[16];
    float hiA = -1e30f, loA = 1e30f, hiB = -1e30f, loB = 1e30f;
#pragma unroll
    for (int i = 0; i < 4; i++) {
        float4 aA = make_float4(0.f, 0.f, 0.f, 0.f);
        float4 aB = make_float4(0.f, 0.f, 0.f, 0.f);
#pragma unroll
        for (int c = 0; c < 10; c++) {
            const float4 kv = reinterpret_cast<const float4*>(kTb + c * NN)[i * 256 + t];
            aA.x = fmaf(qA[c], kv.x, aA.x); aA.y = fmaf(qA[c], kv.y, aA.y);
            aA.z = fmaf(qA[c], kv.z, aA.z); aA.w = fmaf(qA[c], kv.w, aA.w);
            aB.x = fmaf(qB[c], kv.x, aB.x); aB.y = fmaf(qB[c], kv.y, aB.y);
            aB.z = fmaf(qB[c], kv.z, aB.z); aB.w = fmaf(qB[c], kv.w, aB.w);
        }
        scA[i * 4 + 0] = aA.x; scA[i * 4 + 1] = aA.y;
        scA[i * 4 + 2] = aA.z; scA[i * 4 + 3] = aA.w;
        reinterpret_cast<float4*>(suB)[i * 256 + t] = aB;
        hiA = fmaxf(hiA, fmaxf(fmaxf(aA.x, aA.y), fmaxf(aA.z, aA.w)));
        loA = fminf(loA, fminf(fminf(aA.x, aA.y), fminf(aA.z, aA.w)));
        hiB = fmaxf(hiB, fmaxf(fmaxf(aB.x, aB.y), fmaxf(aB.z, aB.w)));
        loB = fminf(loB, fminf(fminf(aB.x, aB.y), fminf(aB.z, aB.w)));
    }
#pragma unroll
    for (int off = 32; off > 0; off >>= 1) {
        hiA = fmaxf(hiA, __shfl_xor(hiA, off));
        loA = fminf(loA, __shfl_xor(loA, off));
        hiB = fmaxf(hiB, __shfl_xor(hiB, off));
        loB = fminf(loB, __shfl_xor(loB, off));
    }

#pragma unroll 1
    for (int rr = 0; rr < 2; rr++) {
        const int row = row0 + rr;
        // broadcast hi/lo for this row; zero hist + cand under one barrier
        if (lane == 0) {
            hpart[w] = rr ? hiB : hiA;
            lpart[w] = rr ? loB : loA;
        }
        base_[2 * t] = 0u; base_[2 * t + 1] = 0u;
        if (t < CANDN - 256) cand[256 + t] = 0ULL;
        cand[t] = 0ULL;
        __syncthreads();
        const float hi = fmaxf(fmaxf(hpart[0], hpart[1]), fmaxf(hpart[2], hpart[3]));
        const float lo = fminf(fminf(lpart[0], lpart[1]), fminf(lpart[2], lpart[3]));
        const bool degen = (hi <= lo);

        // this row's 16 scores -> registers (A: moves; B: 4x ds_read_b128)
        float s[16];
        if (rr == 0) {
#pragma unroll
            for (int i = 0; i < 16; i++) s[i] = scA[i];
        } else {
#pragma unroll
            for (int i = 0; i < 4; i++) {
                const float4 sv = reinterpret_cast<const float4*>(suB)[i * 256 + t];
                s[i * 4 + 0] = sv.x; s[i * 4 + 1] = sv.y;
                s[i * 4 + 2] = sv.z; s[i * 4 + 3] = sv.w;
            }
        }

        float pv = 0.f;
        int jj = 0, p = KSEL;
        bool selected = false;
        const float smax = hi * QKSCALE;

        if (!degen) {
            const float scale = (float)(NBINS - 1) / (hi - lo);
            int bins[16];

            // ---- P2: histogram (bins cached in regs) ----
#pragma unroll
            for (int i = 0; i < 16; i++) {
                const int bin = (int)fminf((s[i] - lo) * scale, (float)(NBINS - 1));
                bins[i] = bin;
                atomicAdd(&base_[bin], 1u);
            }
            __syncthreads();

            // ---- P3: suffix scan -> base (pristine) + bc (mutable) ----
            {
                const unsigned int c0 = base_[2 * t];
                const unsigned int c1 = base_[2 * t + 1];
                const unsigned int T_ = c0 + c1;
                unsigned int acc = T_;
#pragma unroll
                for (int off = 1; off < 64; off <<= 1) {
                    unsigned int o = __shfl_down(acc, off);
                    if (lane + off < 64) acc += o;
                }
                if (lane == 0) wtot[w] = acc;
                __syncthreads();
                unsigned int tail = 0u;
#pragma unroll
                for (int w2 = 1; w2 < 4; w2++) if (w2 > w) tail += wtot[w2];
                const unsigned int A = (acc - T_) + tail;
                base_[2 * t + 1] = A;
                base_[2 * t] = A + c1;
                bc_[2 * t + 1] = A;
                bc_[2 * t] = A + c1;
            }
            __syncthreads();

            // ---- P4: scatter candidates ----
#pragma unroll
            for (int i = 0; i < 16; i++) {
                const int bin = bins[i];
                const unsigned int bs = base_[bin];
                if (bs < KSEL) {
                    const unsigned int pos = atomicAdd(&bc_[bin], 1u);
                    if (pos < CANDN) {
                        const int j = (i >> 2) * 1024 + t * 4 + (i & 3);
                        cand[pos] = (((unsigned long long)enc_key(s[i])) << 16)
                                  | (unsigned long long)(4095 - j);
                    }
                }
            }
            __syncthreads();

            // ---- P5: within-bin rank -> exact sorted position ----
            if (t < CANDN) {
                const unsigned long long mine = cand[t];
                if (mine != 0ULL) {
                    const float sv = dec_key((unsigned int)(mine >> 16));
                    const int bin = (int)fminf((sv - lo) * scale, (float)(NBINS - 1));
                    const unsigned int bs = base_[bin];
                    unsigned int e2 = (bin > 0) ? base_[bin - 1] : 4096u;
                    if (e2 > CANDN) e2 = CANDN;
                    unsigned int rank = 0;
                    for (unsigned int s2 = bs; s2 < e2; s2++)
                        rank += (cand[s2] > mine) ? 1u : 0u;
                    const unsigned int pp = bs + rank;
                    if (pp < KSEL) {
                        selected = true;
                        p = (int)pp;
                        jj = 4095 - (int)(mine & 0xFFFFu);
                        pv = expf(sv * QKSCALE - smax);
                    }
                }
            }
        } else {
            if (t < KSEL) { selected = true; p = t; jj = t; pv = 1.f; }
        }

        // ---- P6: softmax denom ----
        float dsum = pv;
#pragma unroll
        for (int off = 32; off > 0; off >>= 1) dsum += __shfl_xor(dsum, off);
        if (lane == 0) fpart[w] = dsum;
        __syncthreads();
        const float inv = 1.f / (fpart[0] + fpart[1] + fpart[2] + fpart[3]);

        // ---- P7: probs out + ctx ----
        float cx0 = 0.f, cx1 = 0.f, cx2 = 0.f, cx3 = 0.f, cx4 = 0.f;
        float cx5 = 0.f, cx6 = 0.f, cx7 = 0.f, cx8 = 0.f, cx9 = 0.f;
        if (selected) {
            const float pn = pv * inv;
            out_probs[(size_t)row * KSEL + p] = pn;
            const float* vr = vbuf + ((size_t)b_ * NN + (size_t)jj) * 10;
            const float2 v01 = reinterpret_cast<const float2*>(vr)[0];
            const float2 v23 = reinterpret_cast<const float2*>(vr)[1];
            const float2 v45 = reinterpret_cast<const float2*>(vr)[2];
            const float2 v67 = reinterpret_cast<const float2*>(vr)[3];
            const float2 v89 = reinterpret_cast<const float2*>(vr)[4];
            cx0 = pn * v01.x; cx1 = pn * v01.y;
            cx2 = pn * v23.x; cx3 = pn * v23.y;
            cx4 = pn * v45.x; cx5 = pn * v45.y;
            cx6 = pn * v67.x; cx7 = pn * v67.y;
            cx8 = pn * v89.x; cx9 = pn * v89.y;
        }
#pragma unroll
        for (int off = 32; off > 0; off >>= 1) {
            cx0 += __shfl_xor(cx0, off); cx1 += __shfl_xor(cx1, off);
            cx2 += __shfl_xor(cx2, off); cx3 += __shfl_xor(cx3, off);
            cx4 += __shfl_xor(cx4, off); cx5 += __shfl_xor(cx5, off);
            cx6 += __shfl_xor(cx6, off); cx7 += __shfl_xor(cx7, off);
            cx8 += __shfl_xor(cx8, off); cx9 += __shfl_xor(cx9, off);
        }
        if (lane == 0) {
            ctxp[w * 10 + 0] = cx0; ctxp[w * 10 + 1] = cx1; ctxp[w * 10 + 2] = cx2;
            ctxp[w * 10 + 3] = cx3; ctxp[w * 10 + 4] = cx4; ctxp[w * 10 + 5] = cx5;
            ctxp[w * 10 + 6] = cx6; ctxp[w * 10 + 7] = cx7; ctxp[w * 10 + 8] = cx8;
            ctxp[w * 10 + 9] = cx9;
        }
        __syncthreads();
        if (t < 10) ctx_sh[t] = ctxp[t] + ctxp[10 + t] + ctxp[20 + t] + ctxp[30 + t];
        __syncthreads();

        // ---- P8: attn projection + mil logits -> atomic pooled ----
        if (t < 14) {
            float a = b_attn[t];
#pragma unroll
            for (int d = 0; d < 10; d++) a = fmaf(ctx_sh[d], w_attn[t * 10 + d], a);
            attn_sh[t] = a;
        }
        __syncthreads();
        if (t < 2) {
            float lg = b_mil[t];
#pragma unroll
            for (int ii = 0; ii < 14; ii++) lg = fmaf(attn_sh[ii], w_mil[t * 14 + ii], lg);
            atomicAdd(&out_pooled[b_ * 2 + t], lg * (1.f / 4096.f));
        }
        __syncthreads();   // protect shared buffers before next row
    }
}

extern "C" void kernel_launch(void* const* d_in, const int* in_sizes, int n_in,
                              void* d_out, int out_size, void* d_ws, size_t ws_size,
                              hipStream_t stream) {
    const float* x  = (const float*)d_in[0];
    const float* w2 = (const float*)d_in[1];  const float* b2 = (const float*)d_in[2];
    const float* w3 = (const float*)d_in[3];  const float* b3 = (const float*)d_in[4];
    const float* w4 = (const float*)d_in[5];  const float* b4 = (const float*)d_in[6];
    const float* w5 = (const float*)d_in[7];  const float* b5 = (const float*)d_in[8];
    const float* w6 = (const float*)d_in[9];  const float* b6 = (const float*)d_in[10];
    const float* w7 = (const float*)d_in[11]; const float* b7 = (const float*)d_in[12];
    const float* wq = (const float*)d_in[13]; const float* bq = (const float*)d_in[14];
    const float* wk = (const float*)d_in[15]; const float* bk = (const float*)d_in[16];
    const float* wv = (const float*)d_in[17]; const float* bv = (const float*)d_in[18];
    const float* wat = (const float*)d_in[19]; const float* bat = (const float*)d_in[20];
    const float* wm = (const float*)d_in[21];  const float* bm = (const float*)d_in[22];

    float* ws = (float*)d_ws;
    float* qb = ws + WS_Q;
    float* kT = ws + WS_KT;
    float* vb = ws + WS_V;
    float* out = (float*)d_out;

    hipLaunchKernelGGL(featqkv_kernel, dim3(NB * NN / SEQ_PER_BLOCK), dim3(256), 0, stream,
                       x, w2, b2, w3, b3, w4, b4, w5, b5, w6, b6, w7, b7,
                       wq, bq, wk, bk, wv, bv, qb, kT, vb, out);
    hipLaunchKernelGGL(attn_kernel, dim3(NB * NN / 2), dim3(256), 0, stream,
                       qb, kT, vb, wat, bat, wm, bm, out + 8, out);
}

// Round 7
// 362.439 us; speedup vs baseline: 1.3036x; 1.0035x over previous
//
#include <hip/hip_runtime.h>
#include <math.h>

#define NB 4
#define NN 4096
#define KSEL 204
#define NBINS 512
#define CANDN 320
#define QKSCALE 0.31622776601683794f

// workspace layout in floats
#define WS_Q 0
#define WS_KT (NB * NN * 10)       // 163840
#define WS_V (2 * NB * NN * 10)    // 327680

#define SEQ_PER_BLOCK 16

__global__ __launch_bounds__(256, 4) void featqkv_kernel(
    const float* __restrict__ x,
    const float* __restrict__ w2, const float* __restrict__ b2,
    const float* __restrict__ w3, const float* __restrict__ b3,
    const float* __restrict__ w4, const float* __restrict__ b4,
    const float* __restrict__ w5, const float* __restrict__ b5,
    const float* __restrict__ w6, const float* __restrict__ b6,
    const float* __restrict__ w7, const float* __restrict__ b7,
    const float* __restrict__ wq, const float* __restrict__ bq,
    const float* __restrict__ wk, const float* __restrict__ bk,
    const float* __restrict__ wv, const float* __restrict__ bv,
    float* __restrict__ q_out, float* __restrict__ kT_out, float* __restrict__ v_out,
    float* __restrict__ out_pooled)
{
    // x rows padded to 32 floats (128 B) -> all LDS reads are float4-aligned
    __shared__ __align__(16) float xs[SEQ_PER_BLOCK * 480];   // [seq][15][32]
    __shared__ __align__(16) float wpad[14 * 120];            // [ch][15][8]
    __shared__ float bconv[14];
    __shared__ float wqkv[420];
    __shared__ float bqkv[30];
    __shared__ float feats[SEQ_PER_BLOCK * 14];

    const int t = threadIdx.x;
    const int g0 = blockIdx.x * SEQ_PER_BLOCK;

    if (blockIdx.x == 0 && t < 8) out_pooled[t] = 0.f;  // zero pooled accumulators

    // ---- stage x (float4 in, float4 out to padded layout) ----
    const float4* xg4 = reinterpret_cast<const float4*>(x + (size_t)g0 * 360);
    for (int i = t; i < SEQ_PER_BLOCK * 90; i += 256) {
        const int seq = i / 90;
        const int i4 = i % 90;
        const int c = i4 / 6;
        const int u4 = i4 % 6;
        reinterpret_cast<float4*>(&xs[seq * 480 + c * 32])[u4] = xg4[i];
    }
    for (int i = t; i < SEQ_PER_BLOCK * 30; i += 256) {   // pad cols 24..31 = 0
        const int seq = i / 30;
        const int rem = i % 30;
        const int c = rem / 2;
        const int k4 = rem % 2;
        reinterpret_cast<float4*>(&xs[seq * 480 + c * 32 + 24])[k4] =
            make_float4(0.f, 0.f, 0.f, 0.f);
    }
    // ---- stage padded weights [ch][c][8], taps >= h zero ----
    for (int i = t; i < 14 * 120; i += 256) {
        const int ch = i / 120;
        const int rem = i % 120;
        const int c = rem / 8;
        const int j = rem % 8;
        float v = 0.f;
        if (ch < 3)       { if (j < 2) v = w2[ch * 30 + c * 2 + j]; }
        else if (ch < 6)  { if (j < 3) v = w3[(ch - 3) * 45 + c * 3 + j]; }
        else if (ch < 9)  { if (j < 4) v = w4[(ch - 6) * 60 + c * 4 + j]; }
        else if (ch < 11) { if (j < 5) v = w5[(ch - 9) * 75 + c * 5 + j]; }
        else if (ch < 13) { if (j < 6) v = w6[(ch - 11) * 90 + c * 6 + j]; }
        else              { if (j < 7) v = w7[c * 7 + j]; }
        wpad[i] = v;
    }
    if (t < 3) bconv[t] = b2[t];
    else if (t < 6) bconv[t] = b3[t - 3];
    else if (t < 9) bconv[t] = b4[t - 6];
    else if (t < 11) bconv[t] = b5[t - 9];
    else if (t < 13) bconv[t] = b6[t - 11];
    else if (t == 13) bconv[t] = b7[0];
    for (int i = t; i < 140; i += 256) wqkv[i] = wq[i];
    for (int i = t; i < 140; i += 256) wqkv[140 + i] = wk[i];
    for (int i = t; i < 140; i += 256) wqkv[280 + i] = wv[i];
    if (t < 10) bqkv[t] = bq[t];
    else if (t < 20) bqkv[t] = bk[t - 10];
    else if (t < 30) bqkv[t] = bv[t - 20];
    __syncthreads();

    const int seq = t >> 4;
    const int wkr = t & 15;

    if (wkr < 14) {
        const int ch = wkr;
        const int h = (ch < 3) ? 2 : (ch < 6) ? 3 : (ch < 9) ? 4 :
                      (ch < 11) ? 5 : (ch < 13) ? 6 : 7;
        const int T = 25 - h;

        float acc[23];
#pragma unroll
        for (int i2 = 0; i2 < 23; i2++) acc[i2] = 0.f;
        const float4* xrow4 = reinterpret_cast<const float4*>(&xs[seq * 480]);
        const float4* wrow4 = reinterpret_cast<const float4*>(&wpad[ch * 120]);
        for (int c = 0; c < 15; c++) {
            float xr[32];
#pragma unroll
            for (int u4 = 0; u4 < 8; u4++) {
                const float4 rv = xrow4[c * 8 + u4];
                xr[u4 * 4 + 0] = rv.x; xr[u4 * 4 + 1] = rv.y;
                xr[u4 * 4 + 2] = rv.z; xr[u4 * 4 + 3] = rv.w;
            }
            const float4 w0 = wrow4[c * 2];
            const float4 w1 = wrow4[c * 2 + 1];
            float wv[7];
            wv[0] = w0.x; wv[1] = w0.y; wv[2] = w0.z; wv[3] = w0.w;
            wv[4] = w1.x; wv[5] = w1.y; wv[6] = w1.z;
#pragma unroll
            for (int j = 0; j < 7; j++) {
#pragma unroll
                for (int tt = 0; tt < 23; tt++)
                    acc[tt] = fmaf(xr[tt + j], wv[j], acc[tt]);
            }
        }
        float m = -1e30f;
#pragma unroll
        for (int tt = 0; tt < 23; tt++) {
            if (tt < T) m = fmaxf(m, acc[tt]);   // runtime mask only here
        }
        feats[seq * 14 + ch] = fmaxf(m + bconv[ch], 0.f);
    }
    __syncthreads();

    const int g = g0 + seq;
    const int b_ = g >> 12;
    const int n_ = g & 4095;
    for (int o = wkr; o < 30; o += 16) {
        const int type = o / 10;
        const int comp = o % 10;
        const float* wrow = &wqkv[type * 140 + comp * 14];
        const float* frow = &feats[seq * 14];
        float a = bqkv[type * 10 + comp];
#pragma unroll
        for (int ii = 0; ii < 14; ii++) a = fmaf(frow[ii], wrow[ii], a);
        if (type == 0) q_out[(size_t)g * 10 + comp] = a;
        else if (type == 1) kT_out[((size_t)b_ * 10 + comp) * NN + n_] = a;
        else v_out[(size_t)g * 10 + comp] = a;
    }
}

__device__ __forceinline__ float dec_key(unsigned int k) {
    return (k & 0x80000000u) ? __uint_as_float(k ^ 0x80000000u)
                             : __uint_as_float(~k);
}
__device__ __forceinline__ unsigned int enc_key(float s) {
    unsigned int u = __float_as_uint(s);
    return (u & 0x80000000u) ? ~u : (u | 0x80000000u);
}

// 256 threads / 1 row per block (validated G=1 structure, R4-bench 140us).
// Scores in registers; linear-histogram rank; fused pooled epilogue.
__global__ __launch_bounds__(256, 6) void attn_kernel(
    const float* __restrict__ qbuf, const float* __restrict__ kTbuf,
    const float* __restrict__ vbuf,
    const float* __restrict__ w_attn, const float* __restrict__ b_attn,
    const float* __restrict__ w_mil, const float* __restrict__ b_mil,
    float* __restrict__ out_probs, float* __restrict__ out_pooled)
{
    __shared__ unsigned int base_[NBINS];   // counts -> suffix-above (pristine)
    __shared__ unsigned int bc_[NBINS];     // mutable scatter counters
    __shared__ unsigned long long cand[CANDN];
    __shared__ float hpart[4], lpart[4], fpart[4];
    __shared__ unsigned int wtot[4];
    __shared__ float ctxp[40];
    __shared__ float ctx_sh[10];
    __shared__ float attn_sh[14];

    const int t = threadIdx.x;
    const int lane = t & 63;
    const int w = t >> 6;
    const int row = blockIdx.x;
    const int b_ = row >> 12;

    // ---- P1: scores (registers) + block min/max ----
    float q0, q1, q2, q3, q4, q5, q6, q7, q8, q9;
    {
        const float* qp = qbuf + (size_t)row * 10;
        q0 = qp[0]; q1 = qp[1]; q2 = qp[2]; q3 = qp[3]; q4 = qp[4];
        q5 = qp[5]; q6 = qp[6]; q7 = qp[7]; q8 = qp[8]; q9 = qp[9];
    }
    const float* kTb = kTbuf + (size_t)b_ * 10 * NN;
    float sc[16];
    float vhi = -1e30f, vlo = 1e30f;
#pragma unroll
    for (int i = 0; i < 4; i++) {
        float4 a0 = make_float4(0.f, 0.f, 0.f, 0.f);
#pragma unroll
        for (int c = 0; c < 10; c++) {
            const float qc = (c == 0) ? q0 : (c == 1) ? q1 : (c == 2) ? q2 : (c == 3) ? q3 :
                             (c == 4) ? q4 : (c == 5) ? q5 : (c == 6) ? q6 : (c == 7) ? q7 :
                             (c == 8) ? q8 : q9;
            const float4 kv = reinterpret_cast<const float4*>(kTb + c * NN)[i * 256 + t];
            a0.x = fmaf(qc, kv.x, a0.x);
            a0.y = fmaf(qc, kv.y, a0.y);
            a0.z = fmaf(qc, kv.z, a0.z);
            a0.w = fmaf(qc, kv.w, a0.w);
        }
        sc[i * 4 + 0] = a0.x; sc[i * 4 + 1] = a0.y;
        sc[i * 4 + 2] = a0.z; sc[i * 4 + 3] = a0.w;
        vhi = fmaxf(vhi, fmaxf(fmaxf(a0.x, a0.y), fmaxf(a0.z, a0.w)));
        vlo = fminf(vlo, fminf(fminf(a0.x, a0.y), fminf(a0.z, a0.w)));
    }
#pragma unroll
    for (int off = 32; off > 0; off >>= 1) {
        vhi = fmaxf(vhi, __shfl_xor(vhi, off));
        vlo = fminf(vlo, __shfl_xor(vlo, off));
    }
    if (lane == 0) { hpart[w] = vhi; lpart[w] = vlo; }
    // zero hist + cand under same barrier
    base_[2 * t] = 0u; base_[2 * t + 1] = 0u;
    cand[t] = 0ULL;
    if (t < CANDN - 256) cand[256 + t] = 0ULL;
    __syncthreads();
    const float hi = fmaxf(fmaxf(hpart[0], hpart[1]), fmaxf(hpart[2], hpart[3]));
    const float lo = fminf(fminf(lpart[0], lpart[1]), fminf(lpart[2], lpart[3]));
    const bool degen = (hi <= lo);

    float pv = 0.f;
    int jj = 0, p = KSEL;
    bool selected = false;
    const float smax = hi * QKSCALE;

    if (!degen) {
        const float scale = (float)(NBINS - 1) / (hi - lo);
        int bins[16];

        // ---- P2: 512-bin linear histogram (bins cached in regs) ----
#pragma unroll
        for (int i = 0; i < 16; i++) {
            const int bin = (int)fminf((sc[i] - lo) * scale, (float)(NBINS - 1));
            bins[i] = bin;
            atomicAdd(&base_[bin], 1u);
        }
        __syncthreads();

        // ---- P3: suffix scan (2 bins/thread) -> base (pristine) + bc (mutable) ----
        {
            const unsigned int c0 = base_[2 * t];
            const unsigned int c1 = base_[2 * t + 1];
            const unsigned int T_ = c0 + c1;
            unsigned int acc = T_;
#pragma unroll
            for (int off = 1; off < 64; off <<= 1) {
                unsigned int o = __shfl_down(acc, off);
                if (lane + off < 64) acc += o;
            }
            if (lane == 0) wtot[w] = acc;
            __syncthreads();
            unsigned int tail = 0u;
#pragma unroll
            for (int w2 = 1; w2 < 4; w2++) if (w2 > w) tail += wtot[w2];
            const unsigned int A = (acc - T_) + tail;   // keys in bins > 2t+1
            base_[2 * t + 1] = A;
            base_[2 * t] = A + c1;
            bc_[2 * t + 1] = A;
            bc_[2 * t] = A + c1;
        }
        __syncthreads();

        // ---- P4: scatter candidate keys (bins whose base < KSEL) ----
#pragma unroll
        for (int i = 0; i < 16; i++) {
            const int bin = bins[i];
            const unsigned int bs = base_[bin];
            if (bs < KSEL) {
                const unsigned int pos = atomicAdd(&bc_[bin], 1u);
                if (pos < CANDN) {
                    const int j = (i >> 2) * 1024 + t * 4 + (i & 3);
                    cand[pos] = (((unsigned long long)enc_key(sc[i])) << 16)
                              | (unsigned long long)(4095 - j);
                }
            }
        }
        __syncthreads();

        // ---- P5: within-bin rank -> exact sorted position ----
        const unsigned long long mine = cand[t];
        if (mine != 0ULL) {
            const float s = dec_key((unsigned int)(mine >> 16));
            const int bin = (int)fminf((s - lo) * scale, (float)(NBINS - 1));
            const unsigned int bs = base_[bin];
            unsigned int e2 = (bin > 0) ? base_[bin - 1] : 4096u;
            if (e2 > CANDN) e2 = CANDN;
            unsigned int rank = 0;
            for (unsigned int s2 = bs; s2 < e2; s2++)
                rank += (cand[s2] > mine) ? 1u : 0u;
            const unsigned int pp = bs + rank;
            if (pp < KSEL) {
                selected = true;
                p = (int)pp;
                jj = 4095 - (int)(mine & 0xFFFFu);
                pv = expf(s * QKSCALE - smax);
            }
        }
    } else {
        // all scores equal: top-K = lowest indices, uniform softmax
        if (t < KSEL) { selected = true; p = t; jj = t; pv = 1.f; }
    }

    // ---- P6: softmax denom ----
    float dsum = pv;
#pragma unroll
    for (int off = 32; off > 0; off >>= 1) dsum += __shfl_xor(dsum, off);
    if (lane == 0) fpart[w] = dsum;
    __syncthreads();
    const float inv = 1.f / (fpart[0] + fpart[1] + fpart[2] + fpart[3]);

    // ---- P7: probs out + ctx ----
    float cx0 = 0.f, cx1 = 0.f, cx2 = 0.f, cx3 = 0.f, cx4 = 0.f;
    float cx5 = 0.f, cx6 = 0.f, cx7 = 0.f, cx8 = 0.f, cx9 = 0.f;
    if (selected) {
        const float pn = pv * inv;
        out_probs[(size_t)row * KSEL + p] = pn;
        const float* vr = vbuf + ((size_t)b_ * NN + (size_t)jj) * 10;
        const float2 v01 = reinterpret_cast<const float2*>(vr)[0];
        const float2 v23 = reinterpret_cast<const float2*>(vr)[1];
        const float2 v45 = reinterpret_cast<const float2*>(vr)[2];
        const float2 v67 = reinterpret_cast<const float2*>(vr)[3];
        const float2 v89 = reinterpret_cast<const float2*>(vr)[4];
        cx0 = pn * v01.x; cx1 = pn * v01.y;
        cx2 = pn * v23.x; cx3 = pn * v23.y;
        cx4 = pn * v45.x; cx5 = pn * v45.y;
        cx6 = pn * v67.x; cx7 = pn * v67.y;
        cx8 = pn * v89.x; cx9 = pn * v89.y;
    }
#pragma unroll
    for (int off = 32; off > 0; off >>= 1) {
        cx0 += __shfl_xor(cx0, off); cx1 += __shfl_xor(cx1, off);
        cx2 += __shfl_xor(cx2, off); cx3 += __shfl_xor(cx3, off);
        cx4 += __shfl_xor(cx4, off); cx5 += __shfl_xor(cx5, off);
        cx6 += __shfl_xor(cx6, off); cx7 += __shfl_xor(cx7, off);
        cx8 += __shfl_xor(cx8, off); cx9 += __shfl_xor(cx9, off);
    }
    if (lane == 0) {
        ctxp[w * 10 + 0] = cx0; ctxp[w * 10 + 1] = cx1; ctxp[w * 10 + 2] = cx2;
        ctxp[w * 10 + 3] = cx3; ctxp[w * 10 + 4] = cx4; ctxp[w * 10 + 5] = cx5;
        ctxp[w * 10 + 6] = cx6; ctxp[w * 10 + 7] = cx7; ctxp[w * 10 + 8] = cx8;
        ctxp[w * 10 + 9] = cx9;
    }
    __syncthreads();
    if (t < 10) ctx_sh[t] = ctxp[t] + ctxp[10 + t] + ctxp[20 + t] + ctxp[30 + t];
    __syncthreads();

    // ---- P8: attn projection + mil logits -> atomic pooled ----
    if (t < 14) {
        float a = b_attn[t];
#pragma unroll
        for (int d = 0; d < 10; d++) a = fmaf(ctx_sh[d], w_attn[t * 10 + d], a);
        attn_sh[t] = a;
    }
    __syncthreads();
    if (t < 2) {
        float lg = b_mil[t];
#pragma unroll
        for (int ii = 0; ii < 14; ii++) lg = fmaf(attn_sh[ii], w_mil[t * 14 + ii], lg);
        atomicAdd(&out_pooled[b_ * 2 + t], lg * (1.f / 4096.f));
    }
}

extern "C" void kernel_launch(void* const* d_in, const int* in_sizes, int n_in,
                              void* d_out, int out_size, void* d_ws, size_t ws_size,
                              hipStream_t stream) {
    const float* x  = (const float*)d_in[0];
    const float* w2 = (const float*)d_in[1];  const float* b2 = (const float*)d_in[2];
    const float* w3 = (const float*)d_in[3];  const float* b3 = (const float*)d_in[4];
    const float* w4 = (const float*)d_in[5];  const float* b4 = (const float*)d_in[6];
    const float* w5 = (const float*)d_in[7];  const float* b5 = (const float*)d_in[8];
    const float* w6 = (const float*)d_in[9];  const float* b6 = (const float*)d_in[10];
    const float* w7 = (const float*)d_in[11]; const float* b7 = (const float*)d_in[12];
    const float* wq = (const float*)d_in[13]; const float* bq = (const float*)d_in[14];
    const float* wk = (const float*)d_in[15]; const float* bk = (const float*)d_in[16];
    const float* wv = (const float*)d_in[17]; const float* bv = (const float*)d_in[18];
    const float* wat = (const float*)d_in[19]; const float* bat = (const float*)d_in[20];
    const float* wm = (const float*)d_in[21];  const float* bm = (const float*)d_in[22];

    float* ws = (float*)d_ws;
    float* qb = ws + WS_Q;
    float* kT = ws + WS_KT;
    float* vb = ws + WS_V;
    float* out = (float*)d_out;

    hipLaunchKernelGGL(featqkv_kernel, dim3(NB * NN / SEQ_PER_BLOCK), dim3(256), 0, stream,
                       x, w2, b2, w3, b3, w4, b4, w5, b5, w6, b6, w7, b7,
                       wq, bq, wk, bk, wv, bv, qb, kT, vb, out);
    hipLaunchKernelGGL(attn_kernel, dim3(NB * NN), dim3(256), 0, stream,
                       qb, kT, vb, wat, bat, wm, bm, out + 8, out);
}

// Round 9
// 271.683 us; speedup vs baseline: 1.7391x; 1.3341x over previous
//
#include <hip/hip_runtime.h>
#include <math.h>

#define NB 4
#define NN 4096
#define KSEL 204
#define NBINS 512
#define CANDN 320
#define QKSCALE 0.31622776601683794f

// workspace layout in floats
#define WS_Q 0
#define WS_KT (NB * NN * 10)       // 163840
#define WS_V (2 * NB * NN * 10)    // 327680
#define WS_LG (3 * NB * NN * 10)   // 491520  (+ NB*NN*2 = 32768)

#define SEQ_PER_BLOCK 16

__global__ __launch_bounds__(256, 4) void featqkv_kernel(
    const float* __restrict__ x,
    const float* __restrict__ w2, const float* __restrict__ b2,
    const float* __restrict__ w3, const float* __restrict__ b3,
    const float* __restrict__ w4, const float* __restrict__ b4,
    const float* __restrict__ w5, const float* __restrict__ b5,
    const float* __restrict__ w6, const float* __restrict__ b6,
    const float* __restrict__ w7, const float* __restrict__ b7,
    const float* __restrict__ wq, const float* __restrict__ bq,
    const float* __restrict__ wk, const float* __restrict__ bk,
    const float* __restrict__ wv, const float* __restrict__ bv,
    float* __restrict__ q_out, float* __restrict__ kT_out, float* __restrict__ v_out)
{
    // x rows padded to 32 floats (128 B) -> all LDS reads are float4-aligned
    __shared__ __align__(16) float xs[SEQ_PER_BLOCK * 480];   // [seq][15][32]
    __shared__ __align__(16) float wpad[14 * 120];            // [ch][15][8]
    __shared__ float bconv[14];
    __shared__ float wqkv[420];
    __shared__ float bqkv[30];
    __shared__ float feats[SEQ_PER_BLOCK * 14];

    const int t = threadIdx.x;
    const int g0 = blockIdx.x * SEQ_PER_BLOCK;

    // ---- stage x (float4 in, float4 out to padded layout) ----
    const float4* xg4 = reinterpret_cast<const float4*>(x + (size_t)g0 * 360);
    for (int i = t; i < SEQ_PER_BLOCK * 90; i += 256) {
        const int seq = i / 90;
        const int i4 = i % 90;
        const int c = i4 / 6;
        const int u4 = i4 % 6;
        reinterpret_cast<float4*>(&xs[seq * 480 + c * 32])[u4] = xg4[i];
    }
    for (int i = t; i < SEQ_PER_BLOCK * 30; i += 256) {   // pad cols 24..31 = 0
        const int seq = i / 30;
        const int rem = i % 30;
        const int c = rem / 2;
        const int k4 = rem % 2;
        reinterpret_cast<float4*>(&xs[seq * 480 + c * 32 + 24])[k4] =
            make_float4(0.f, 0.f, 0.f, 0.f);
    }
    // ---- stage padded weights [ch][c][8], taps >= h zero ----
    for (int i = t; i < 14 * 120; i += 256) {
        const int ch = i / 120;
        const int rem = i % 120;
        const int c = rem / 8;
        const int j = rem % 8;
        float v = 0.f;
        if (ch < 3)       { if (j < 2) v = w2[ch * 30 + c * 2 + j]; }
        else if (ch < 6)  { if (j < 3) v = w3[(ch - 3) * 45 + c * 3 + j]; }
        else if (ch < 9)  { if (j < 4) v = w4[(ch - 6) * 60 + c * 4 + j]; }
        else if (ch < 11) { if (j < 5) v = w5[(ch - 9) * 75 + c * 5 + j]; }
        else if (ch < 13) { if (j < 6) v = w6[(ch - 11) * 90 + c * 6 + j]; }
        else              { if (j < 7) v = w7[c * 7 + j]; }
        wpad[i] = v;
    }
    if (t < 3) bconv[t] = b2[t];
    else if (t < 6) bconv[t] = b3[t - 3];
    else if (t < 9) bconv[t] = b4[t - 6];
    else if (t < 11) bconv[t] = b5[t - 9];
    else if (t < 13) bconv[t] = b6[t - 11];
    else if (t == 13) bconv[t] = b7[0];
    for (int i = t; i < 140; i += 256) wqkv[i] = wq[i];
    for (int i = t; i < 140; i += 256) wqkv[140 + i] = wk[i];
    for (int i = t; i < 140; i += 256) wqkv[280 + i] = wv[i];
    if (t < 10) bqkv[t] = bq[t];
    else if (t < 20) bqkv[t] = bk[t - 10];
    else if (t < 30) bqkv[t] = bv[t - 20];
    __syncthreads();

    const int seq = t >> 4;
    const int wkr = t & 15;

    if (wkr < 14) {
        const int ch = wkr;
        const int h = (ch < 3) ? 2 : (ch < 6) ? 3 : (ch < 9) ? 4 :
                      (ch < 11) ? 5 : (ch < 13) ? 6 : 7;
        const int T = 25 - h;

        float acc[23];
#pragma unroll
        for (int i2 = 0; i2 < 23; i2++) acc[i2] = 0.f;
        const float4* xrow4 = reinterpret_cast<const float4*>(&xs[seq * 480]);
        const float4* wrow4 = reinterpret_cast<const float4*>(&wpad[ch * 120]);
        for (int c = 0; c < 15; c++) {
            float xr[32];
#pragma unroll
            for (int u4 = 0; u4 < 8; u4++) {
                const float4 rv = xrow4[c * 8 + u4];
                xr[u4 * 4 + 0] = rv.x; xr[u4 * 4 + 1] = rv.y;
                xr[u4 * 4 + 2] = rv.z; xr[u4 * 4 + 3] = rv.w;
            }
            const float4 w0 = wrow4[c * 2];
            const float4 w1 = wrow4[c * 2 + 1];
            float wv[7];
            wv[0] = w0.x; wv[1] = w0.y; wv[2] = w0.z; wv[3] = w0.w;
            wv[4] = w1.x; wv[5] = w1.y; wv[6] = w1.z;
#pragma unroll
            for (int j = 0; j < 7; j++) {
#pragma unroll
                for (int tt = 0; tt < 23; tt++)
                    acc[tt] = fmaf(xr[tt + j], wv[j], acc[tt]);
            }
        }
        float m = -1e30f;
#pragma unroll
        for (int tt = 0; tt < 23; tt++) {
            if (tt < T) m = fmaxf(m, acc[tt]);   // runtime mask only here
        }
        feats[seq * 14 + ch] = fmaxf(m + bconv[ch], 0.f);
    }
    __syncthreads();

    const int g = g0 + seq;
    const int b_ = g >> 12;
    const int n_ = g & 4095;
    for (int o = wkr; o < 30; o += 16) {
        const int type = o / 10;
        const int comp = o % 10;
        const float* wrow = &wqkv[type * 140 + comp * 14];
        const float* frow = &feats[seq * 14];
        float a = bqkv[type * 10 + comp];
#pragma unroll
        for (int ii = 0; ii < 14; ii++) a = fmaf(frow[ii], wrow[ii], a);
        if (type == 0) q_out[(size_t)g * 10 + comp] = a;
        else if (type == 1) kT_out[((size_t)b_ * 10 + comp) * NN + n_] = a;
        else v_out[(size_t)g * 10 + comp] = a;
    }
}

__device__ __forceinline__ float dec_key(unsigned int k) {
    return (k & 0x80000000u) ? __uint_as_float(k ^ 0x80000000u)
                             : __uint_as_float(~k);
}
__device__ __forceinline__ unsigned int enc_key(float s) {
    unsigned int u = __float_as_uint(s);
    return (u & 0x80000000u) ? ~u : (u | 0x80000000u);
}

// 256 threads / 1 row per block. Scores in registers; linear-histogram rank.
// Epilogue writes logits to ws (NO global atomics -> no endpgm drain stall).
__global__ __launch_bounds__(256, 6) void attn_kernel(
    const float* __restrict__ qbuf, const float* __restrict__ kTbuf,
    const float* __restrict__ vbuf,
    const float* __restrict__ w_attn, const float* __restrict__ b_attn,
    const float* __restrict__ w_mil, const float* __restrict__ b_mil,
    float* __restrict__ out_probs, float* __restrict__ logits)
{
    __shared__ unsigned int base_[NBINS];   // counts -> suffix-above (pristine)
    __shared__ unsigned int bc_[NBINS];     // mutable scatter counters
    __shared__ unsigned long long cand[CANDN];
    __shared__ float hpart[4], lpart[4], fpart[4];
    __shared__ unsigned int wtot[4];
    __shared__ float ctxp[40];
    __shared__ float ctx_sh[10];
    __shared__ float attn_sh[14];

    const int t = threadIdx.x;
    const int lane = t & 63;
    const int w = t >> 6;
    const int row = blockIdx.x;
    const int b_ = row >> 12;

    // ---- P1: scores (registers) + block min/max ----
    float q0, q1, q2, q3, q4, q5, q6, q7, q8, q9;
    {
        const float* qp = qbuf + (size_t)row * 10;
        q0 = qp[0]; q1 = qp[1]; q2 = qp[2]; q3 = qp[3]; q4 = qp[4];
        q5 = qp[5]; q6 = qp[6]; q7 = qp[7]; q8 = qp[8]; q9 = qp[9];
    }
    const float* kTb = kTbuf + (size_t)b_ * 10 * NN;
    float sc[16];
    float vhi = -1e30f, vlo = 1e30f;
#pragma unroll
    for (int i = 0; i < 4; i++) {
        float4 a0 = make_float4(0.f, 0.f, 0.f, 0.f);
#pragma unroll
        for (int c = 0; c < 10; c++) {
            const float qc = (c == 0) ? q0 : (c == 1) ? q1 : (c == 2) ? q2 : (c == 3) ? q3 :
                             (c == 4) ? q4 : (c == 5) ? q5 : (c == 6) ? q6 : (c == 7) ? q7 :
                             (c == 8) ? q8 : q9;
            const float4 kv = reinterpret_cast<const float4*>(kTb + c * NN)[i * 256 + t];
            a0.x = fmaf(qc, kv.x, a0.x);
            a0.y = fmaf(qc, kv.y, a0.y);
            a0.z = fmaf(qc, kv.z, a0.z);
            a0.w = fmaf(qc, kv.w, a0.w);
        }
        sc[i * 4 + 0] = a0.x; sc[i * 4 + 1] = a0.y;
        sc[i * 4 + 2] = a0.z; sc[i * 4 + 3] = a0.w;
        vhi = fmaxf(vhi, fmaxf(fmaxf(a0.x, a0.y), fmaxf(a0.z, a0.w)));
        vlo = fminf(vlo, fminf(fminf(a0.x, a0.y), fminf(a0.z, a0.w)));
    }
#pragma unroll
    for (int off = 32; off > 0; off >>= 1) {
        vhi = fmaxf(vhi, __shfl_xor(vhi, off));
        vlo = fminf(vlo, __shfl_xor(vlo, off));
    }
    if (lane == 0) { hpart[w] = vhi; lpart[w] = vlo; }
    // zero hist + cand under same barrier
    base_[2 * t] = 0u; base_[2 * t + 1] = 0u;
    cand[t] = 0ULL;
    if (t < CANDN - 256) cand[256 + t] = 0ULL;
    __syncthreads();
    const float hi = fmaxf(fmaxf(hpart[0], hpart[1]), fmaxf(hpart[2], hpart[3]));
    const float lo = fminf(fminf(lpart[0], lpart[1]), fminf(lpart[2], lpart[3]));
    const bool degen = (hi <= lo);

    float pv = 0.f;
    int jj = 0, p = KSEL;
    bool selected = false;
    const float smax = hi * QKSCALE;

    if (!degen) {
        const float scale = (float)(NBINS - 1) / (hi - lo);
        int bins[16];

        // ---- P2: 512-bin linear histogram (bins cached in regs) ----
#pragma unroll
        for (int i = 0; i < 16; i++) {
            const int bin = (int)fminf((sc[i] - lo) * scale, (float)(NBINS - 1));
            bins[i] = bin;
            atomicAdd(&base_[bin], 1u);
        }
        __syncthreads();

        // ---- P3: suffix scan (2 bins/thread) -> base (pristine) + bc (mutable) ----
        {
            const unsigned int c0 = base_[2 * t];
            const unsigned int c1 = base_[2 * t + 1];
            const unsigned int T_ = c0 + c1;
            unsigned int acc = T_;
#pragma unroll
            for (int off = 1; off < 64; off <<= 1) {
                unsigned int o = __shfl_down(acc, off);
                if (lane + off < 64) acc += o;
            }
            if (lane == 0) wtot[w] = acc;
            __syncthreads();
            unsigned int tail = 0u;
#pragma unroll
            for (int w2 = 1; w2 < 4; w2++) if (w2 > w) tail += wtot[w2];
            const unsigned int A = (acc - T_) + tail;   // keys in bins > 2t+1
            base_[2 * t + 1] = A;
            base_[2 * t] = A + c1;
            bc_[2 * t + 1] = A;
            bc_[2 * t] = A + c1;
        }
        __syncthreads();

        // ---- P4: scatter candidate keys (bins whose base < KSEL) ----
#pragma unroll
        for (int i = 0; i < 16; i++) {
            const int bin = bins[i];
            const unsigned int bs = base_[bin];
            if (bs < KSEL) {
                const unsigned int pos = atomicAdd(&bc_[bin], 1u);
                if (pos < CANDN) {
                    const int j = (i >> 2) * 1024 + t * 4 + (i & 3);
                    cand[pos] = (((unsigned long long)enc_key(sc[i])) << 16)
                              | (unsigned long long)(4095 - j);
                }
            }
        }
        __syncthreads();

        // ---- P5: within-bin rank -> exact sorted position ----
        if (t < CANDN) {
            const unsigned long long mine = cand[t];
            if (mine != 0ULL) {
                const float s = dec_key((unsigned int)(mine >> 16));
                const int bin = (int)fminf((s - lo) * scale, (float)(NBINS - 1));
                const unsigned int bs = base_[bin];
                unsigned int e2 = (bin > 0) ? base_[bin - 1] : 4096u;
                if (e2 > CANDN) e2 = CANDN;
                unsigned int rank = 0;
                for (unsigned int s2 = bs; s2 < e2; s2++)
                    rank += (cand[s2] > mine) ? 1u : 0u;
                const unsigned int pp = bs + rank;
                if (pp < KSEL) {
                    selected = true;
                    p = (int)pp;
                    jj = 4095 - (int)(mine & 0xFFFFu);
                    pv = expf(s * QKSCALE - smax);
                }
            }
        }
    } else {
        // all scores equal: top-K = lowest indices, uniform softmax
        if (t < KSEL) { selected = true; p = t; jj = t; pv = 1.f; }
    }

    // ---- P6: softmax denom ----
    float dsum = pv;
#pragma unroll
    for (int off = 32; off > 0; off >>= 1) dsum += __shfl_xor(dsum, off);
    if (lane == 0) fpart[w] = dsum;
    __syncthreads();
    const float inv = 1.f / (fpart[0] + fpart[1] + fpart[2] + fpart[3]);

    // ---- P7: probs out + ctx ----
    float cx0 = 0.f, cx1 = 0.f, cx2 = 0.f, cx3 = 0.f, cx4 = 0.f;
    float cx5 = 0.f, cx6 = 0.f, cx7 = 0.f, cx8 = 0.f, cx9 = 0.f;
    if (selected) {
        const float pn = pv * inv;
        out_probs[(size_t)row * KSEL + p] = pn;
        const float* vr = vbuf + ((size_t)b_ * NN + (size_t)jj) * 10;
        const float2 v01 = reinterpret_cast<const float2*>(vr)[0];
        const float2 v23 = reinterpret_cast<const float2*>(vr)[1];
        const float2 v45 = reinterpret_cast<const float2*>(vr)[2];
        const float2 v67 = reinterpret_cast<const float2*>(vr)[3];
        const float2 v89 = reinterpret_cast<const float2*>(vr)[4];
        cx0 = pn * v01.x; cx1 = pn * v01.y;
        cx2 = pn * v23.x; cx3 = pn * v23.y;
        cx4 = pn * v45.x; cx5 = pn * v45.y;
        cx6 = pn * v67.x; cx7 = pn * v67.y;
        cx8 = pn * v89.x; cx9 = pn * v89.y;
    }
#pragma unroll
    for (int off = 32; off > 0; off >>= 1) {
        cx0 += __shfl_xor(cx0, off); cx1 += __shfl_xor(cx1, off);
        cx2 += __shfl_xor(cx2, off); cx3 += __shfl_xor(cx3, off);
        cx4 += __shfl_xor(cx4, off); cx5 += __shfl_xor(cx5, off);
        cx6 += __shfl_xor(cx6, off); cx7 += __shfl_xor(cx7, off);
        cx8 += __shfl_xor(cx8, off); cx9 += __shfl_xor(cx9, off);
    }
    if (lane == 0) {
        ctxp[w * 10 + 0] = cx0; ctxp[w * 10 + 1] = cx1; ctxp[w * 10 + 2] = cx2;
        ctxp[w * 10 + 3] = cx3; ctxp[w * 10 + 4] = cx4; ctxp[w * 10 + 5] = cx5;
        ctxp[w * 10 + 6] = cx6; ctxp[w * 10 + 7] = cx7; ctxp[w * 10 + 8] = cx8;
        ctxp[w * 10 + 9] = cx9;
    }
    __syncthreads();
    if (t < 10) ctx_sh[t] = ctxp[t] + ctxp[10 + t] + ctxp[20 + t] + ctxp[30 + t];
    __syncthreads();

    // ---- P8: attn projection + mil logits -> plain store to ws ----
    if (t < 14) {
        float a = b_attn[t];
#pragma unroll
        for (int d = 0; d < 10; d++) a = fmaf(ctx_sh[d], w_attn[t * 10 + d], a);
        attn_sh[t] = a;
    }
    __syncthreads();
    if (t < 2) {
        float lg = b_mil[t];
#pragma unroll
        for (int ii = 0; ii < 14; ii++) lg = fmaf(attn_sh[ii], w_mil[t * 14 + ii], lg);
        logits[(size_t)row * 2 + t] = lg;
    }
}

__global__ __launch_bounds__(256) void pool_kernel(
    const float* __restrict__ logits, float* __restrict__ out)
{
    __shared__ float red[256];
    const int t = threadIdx.x;
    const int bc = blockIdx.x;       // 0..7: b = bc>>1, c = bc&1
    const int b_ = bc >> 1;
    const int c_ = bc & 1;
    float a = 0.f;
    for (int n2 = t; n2 < NN; n2 += 256)
        a += logits[((size_t)b_ * NN + n2) * 2 + c_];
    red[t] = a;
    __syncthreads();
    for (int off = 128; off > 0; off >>= 1) {
        if (t < off) red[t] += red[t + off];
        __syncthreads();
    }
    if (t == 0) out[bc] = red[0] * (1.f / 4096.f);
}

extern "C" void kernel_launch(void* const* d_in, const int* in_sizes, int n_in,
                              void* d_out, int out_size, void* d_ws, size_t ws_size,
                              hipStream_t stream) {
    const float* x  = (const float*)d_in[0];
    const float* w2 = (const float*)d_in[1];  const float* b2 = (const float*)d_in[2];
    const float* w3 = (const float*)d_in[3];  const float* b3 = (const float*)d_in[4];
    const float* w4 = (const float*)d_in[5];  const float* b4 = (const float*)d_in[6];
    const float* w5 = (const float*)d_in[7];  const float* b5 = (const float*)d_in[8];
    const float* w6 = (const float*)d_in[9];  const float* b6 = (const float*)d_in[10];
    const float* w7 = (const float*)d_in[11]; const float* b7 = (const float*)d_in[12];
    const float* wq = (const float*)d_in[13]; const float* bq = (const float*)d_in[14];
    const float* wk = (const float*)d_in[15]; const float* bk = (const float*)d_in[16];
    const float* wv = (const float*)d_in[17]; const float* bv = (const float*)d_in[18];
    const float* wat = (const float*)d_in[19]; const float* bat = (const float*)d_in[20];
    const float* wm = (const float*)d_in[21];  const float* bm = (const float*)d_in[22];

    float* ws = (float*)d_ws;
    float* qb = ws + WS_Q;
    float* kT = ws + WS_KT;
    float* vb = ws + WS_V;
    float* lg = ws + WS_LG;
    float* out = (float*)d_out;

    hipLaunchKernelGGL(featqkv_kernel, dim3(NB * NN / SEQ_PER_BLOCK), dim3(256), 0, stream,
                       x, w2, b2, w3, b3, w4, b4, w5, b5, w6, b6, w7, b7,
                       wq, bq, wk, bk, wv, bv, qb, kT, vb);
    hipLaunchKernelGGL(attn_kernel, dim3(NB * NN), dim3(256), 0, stream,
                       qb, kT, vb, wat, bat, wm, bm, out + 8, lg);
    hipLaunchKernelGGL(pool_kernel, dim3(8), dim3(256), 0, stream, lg, out);
}